// Round 1
// baseline (318.362 us; speedup 1.0000x reference)
//
#include <hip/hip_runtime.h>
#include <hip/hip_bf16.h>
#include <stdint.h>

#define H 8
#define NQ 1024
#define NKV 8192
#define DM 256
#define DH 32
#define KVBLK 128
#define KSPLIT 8
#define KSLICE (NKV / KSPLIT)      // 1024
#define NITER (KSLICE / KVBLK)     // 8
#define SCALE 0.17677669529663687f

typedef __attribute__((ext_vector_type(8))) __bf16 bf16x8;
typedef __attribute__((ext_vector_type(4))) float f32x4;

__device__ inline unsigned short f2bf(float f) {
  unsigned int u = __builtin_bit_cast(unsigned int, f);
  u = (u + 0x7FFFu + ((u >> 16) & 1u)) >> 16;
  return (unsigned short)u;
}

// ---------------- weights fp32 -> bf16 ----------------
__global__ void w2bf_kernel(const float* __restrict__ src, unsigned short* __restrict__ dst) {
  int i = (blockIdx.x * 256 + threadIdx.x) * 4;
  float4 v = *(const float4*)(src + i);
  unsigned int lo = (unsigned int)f2bf(v.x) | ((unsigned int)f2bf(v.y) << 16);
  unsigned int hi = (unsigned int)f2bf(v.z) | ((unsigned int)f2bf(v.w) << 16);
  *(uint2*)(dst + i) = make_uint2(lo, hi);
}

// ---------------- LayerNorm (q rows then kv rows) -> bf16 ----------------
__global__ void ln_kernel(const float* __restrict__ qin, const float* __restrict__ kvin,
                          const float* __restrict__ gq, const float* __restrict__ bq,
                          const float* __restrict__ gkv, const float* __restrict__ bkv,
                          unsigned short* __restrict__ qn, unsigned short* __restrict__ kvn) {
  int row = blockIdx.x * 64 + (threadIdx.x >> 2);
  int l4 = threadIdx.x & 3;
  const float* src; const float* ga; const float* be; unsigned short* dst;
  if (row < 2048) {
    src = qin + (long)row * DM; ga = gq; be = bq; dst = qn + (long)row * DM;
  } else {
    int r2 = row - 2048;
    src = kvin + (long)r2 * DM; ga = gkv; be = bkv; dst = kvn + (long)r2 * DM;
  }
  int c0 = l4 * 64;
  float s = 0.f, ss = 0.f;
  float4 xv[16];
#pragma unroll
  for (int i = 0; i < 16; i++) {
    float4 v = *(const float4*)(src + c0 + i * 4);
    xv[i] = v;
    s += v.x + v.y + v.z + v.w;
    ss += v.x * v.x + v.y * v.y + v.z * v.z + v.w * v.w;
  }
  s += __shfl_xor(s, 1, 4);  s += __shfl_xor(s, 2, 4);
  ss += __shfl_xor(ss, 1, 4); ss += __shfl_xor(ss, 2, 4);
  float mean = s * (1.0f / 256.0f);
  float var = ss * (1.0f / 256.0f) - mean * mean;
  float rs = 1.0f / sqrtf(var + 1e-5f);
#pragma unroll
  for (int i = 0; i < 8; i++) {
    float4 a = xv[2 * i], b = xv[2 * i + 1];
    float4 g0 = *(const float4*)(ga + c0 + i * 8);
    float4 g1 = *(const float4*)(ga + c0 + i * 8 + 4);
    float4 b0 = *(const float4*)(be + c0 + i * 8);
    float4 b1 = *(const float4*)(be + c0 + i * 8 + 4);
    unsigned short t[8];
    t[0] = f2bf((a.x - mean) * rs * g0.x + b0.x);
    t[1] = f2bf((a.y - mean) * rs * g0.y + b0.y);
    t[2] = f2bf((a.z - mean) * rs * g0.z + b0.z);
    t[3] = f2bf((a.w - mean) * rs * g0.w + b0.w);
    t[4] = f2bf((b.x - mean) * rs * g1.x + b1.x);
    t[5] = f2bf((b.y - mean) * rs * g1.y + b1.y);
    t[6] = f2bf((b.z - mean) * rs * g1.z + b1.z);
    t[7] = f2bf((b.w - mean) * rs * g1.w + b1.w);
    unsigned int u0 = (unsigned int)t[0] | ((unsigned int)t[1] << 16);
    unsigned int u1 = (unsigned int)t[2] | ((unsigned int)t[3] << 16);
    unsigned int u2 = (unsigned int)t[4] | ((unsigned int)t[5] << 16);
    unsigned int u3 = (unsigned int)t[6] | ((unsigned int)t[7] << 16);
    *(uint4*)(dst + c0 + i * 8) = make_uint4(u0, u1, u2, u3);
  }
}

// ---------------- projection GEMM: out = X @ W^T, head-scattered ----------------
// mode 0: out[((b*H+h)*Nper + i)*32 + dd]   (Q, K layout)
// mode 1: out[((b*H+h)*32 + dd)*Nper + i]   (V transposed layout)
__global__ void proj_kernel(const unsigned short* __restrict__ X, const unsigned short* __restrict__ Wb,
                            unsigned short* __restrict__ out, int Nper, int mode) {
  int w = threadIdx.x >> 6, lane = threadIdx.x & 63;
  int c = lane & 15, g = lane >> 4;
  int mbase = blockIdx.x * 64 + w * 16;
  f32x4 acc[16];
#pragma unroll
  for (int i = 0; i < 16; i++) acc[i] = (f32x4){0.f, 0.f, 0.f, 0.f};
  const unsigned short* arow = X + (long)(mbase + c) * DM + g * 8;
#pragma unroll
  for (int ks = 0; ks < 8; ks++) {
    bf16x8 af = *(const bf16x8*)(arow + ks * 32);
#pragma unroll
    for (int nt = 0; nt < 16; nt++) {
      bf16x8 bf = *(const bf16x8*)(Wb + (long)(nt * 16 + c) * DM + ks * 32 + g * 8);
      acc[nt] = __builtin_amdgcn_mfma_f32_16x16x32_bf16(af, bf, acc[nt], 0, 0, 0);
    }
  }
#pragma unroll
  for (int nt = 0; nt < 16; nt++) {
#pragma unroll
    for (int r = 0; r < 4; r++) {
      int m = mbase + 4 * g + r;
      int n = nt * 16 + c;
      int b = (m >= Nper) ? 1 : 0;
      int i = m - b * Nper;
      int h = n >> 5, dd = n & 31;
      long idx;
      if (mode == 0) idx = ((long)(b * H + h) * Nper + i) * DH + dd;
      else           idx = ((long)(b * H + h) * DH + dd) * (long)Nper + i;
      out[idx] = f2bf(acc[nt][r]);
    }
  }
}

// ---------------- flash attention with bias, KV-split partials ----------------
__global__ __launch_bounds__(256, 4) void attn_kernel(
    const unsigned short* __restrict__ Qw, const unsigned short* __restrict__ Kw,
    const unsigned short* __restrict__ Vtw, const float* __restrict__ bias,
    float* __restrict__ Opart, float* __restrict__ Mpart, float* __restrict__ Lpart) {
  __shared__ __align__(16) unsigned short Klds[KVBLK * 40];
  __shared__ __align__(16) unsigned short Vlds[DH * 136];
  __shared__ __align__(16) unsigned short Plds[4][16 * 136];

  int bx = blockIdx.x;
  int s = bx & 7, qt = (bx >> 3) & 15, bh = bx >> 7;
  int tid = threadIdx.x;
  int w = tid >> 6, lane = tid & 63, c = lane & 15, g = lane >> 4;

  const f32x4 fzero = {0.f, 0.f, 0.f, 0.f};

  bf16x8 qfrag = *(const bf16x8*)(Qw + ((long)(bh * NQ + qt * 64 + w * 16 + c)) * DH + g * 8);

  const float* brow[4];
#pragma unroll
  for (int r = 0; r < 4; r++)
    brow[r] = bias + ((long)bh * NQ + qt * 64 + w * 16 + 4 * g + r) * (long)NKV + s * KSLICE;

  const unsigned short* Kbase = Kw + ((long)bh * NKV + s * KSLICE) * DH;
  const unsigned short* Vbase = Vtw + ((long)bh * DH) * NKV + s * KSLICE;

  float m_run[4] = {-1e30f, -1e30f, -1e30f, -1e30f};
  float l_run[4] = {0.f, 0.f, 0.f, 0.f};
  f32x4 oacc[2] = {fzero, fzero};

  for (int it = 0; it < NITER; it++) {
    int k0 = it * KVBLK;
    // stage K tile [128][32] -> Klds (pitch 40)
    {
      const unsigned short* src = Kbase + (long)k0 * DH;
#pragma unroll
      for (int rp = 0; rp < 2; rp++) {
        int row = (tid >> 2) + rp * 64;
        int q4 = tid & 3;
        *(uint4*)(&Klds[row * 40 + q4 * 8]) = *(const uint4*)(src + row * DH + q4 * 8);
      }
      // stage V^T tile [32][128] -> Vlds (pitch 136)
#pragma unroll
      for (int rp = 0; rp < 2; rp++) {
        int u = tid + rp * 256;
        int d = u >> 4, q16 = u & 15;
        *(uint4*)(&Vlds[d * 136 + q16 * 8]) = *(const uint4*)(Vbase + (long)d * NKV + k0 + q16 * 8);
      }
    }
    __syncthreads();

    // S = Q K^T  (8 k-subtiles of 16)
    f32x4 sacc[8];
#pragma unroll
    for (int t = 0; t < 8; t++) {
      bf16x8 kf = *(const bf16x8*)(&Klds[(t * 16 + c) * 40 + g * 8]);
      sacc[t] = __builtin_amdgcn_mfma_f32_16x16x32_bf16(qfrag, kf, fzero, 0, 0, 0);
    }
    // scale + bias
#pragma unroll
    for (int t = 0; t < 8; t++) {
#pragma unroll
      for (int r = 0; r < 4; r++)
        sacc[t][r] = fmaf(sacc[t][r], SCALE, brow[r][k0 + t * 16 + c]);
    }
    // online softmax: row max
    float mnew[4], al[4], rsum[4];
#pragma unroll
    for (int r = 0; r < 4; r++) {
      float v = -1e30f;
#pragma unroll
      for (int t = 0; t < 8; t++) v = fmaxf(v, sacc[t][r]);
      v = fmaxf(v, __shfl_xor(v, 1, 16));
      v = fmaxf(v, __shfl_xor(v, 2, 16));
      v = fmaxf(v, __shfl_xor(v, 4, 16));
      v = fmaxf(v, __shfl_xor(v, 8, 16));
      mnew[r] = fmaxf(m_run[r], v);
      al[r] = __expf(m_run[r] - mnew[r]);
      m_run[r] = mnew[r];
      rsum[r] = 0.f;
    }
    // P = exp(s - m), stash to LDS (bf16), accumulate row sums
#pragma unroll
    for (int t = 0; t < 8; t++) {
#pragma unroll
      for (int r = 0; r < 4; r++) {
        float p = __expf(sacc[t][r] - mnew[r]);
        rsum[r] += p;
        Plds[w][(4 * g + r) * 136 + t * 16 + c] = f2bf(p);
      }
    }
#pragma unroll
    for (int r = 0; r < 4; r++) {
      float v = rsum[r];
      v += __shfl_xor(v, 1, 16);
      v += __shfl_xor(v, 2, 16);
      v += __shfl_xor(v, 4, 16);
      v += __shfl_xor(v, 8, 16);
      l_run[r] = l_run[r] * al[r] + v;
      oacc[0][r] *= al[r];
      oacc[1][r] *= al[r];
    }
    // O += P @ V   (4 k-chunks of 32, 2 d-tiles of 16)
#pragma unroll
    for (int ch = 0; ch < 4; ch++) {
      bf16x8 pf = *(const bf16x8*)(&Plds[w][c * 136 + ch * 32 + g * 8]);
#pragma unroll
      for (int dt = 0; dt < 2; dt++) {
        bf16x8 vf = *(const bf16x8*)(&Vlds[(dt * 16 + c) * 136 + ch * 32 + g * 8]);
        oacc[dt] = __builtin_amdgcn_mfma_f32_16x16x32_bf16(pf, vf, oacc[dt], 0, 0, 0);
      }
    }
    __syncthreads();
  }
  // write partials
  float* Op = Opart + (long)bx * (64 * 32);
#pragma unroll
  for (int dt = 0; dt < 2; dt++)
#pragma unroll
    for (int r = 0; r < 4; r++)
      Op[(w * 16 + 4 * g + r) * 32 + dt * 16 + c] = oacc[dt][r];
  if (c == 0) {
#pragma unroll
    for (int r = 0; r < 4; r++) {
      Mpart[(long)bx * 64 + w * 16 + 4 * g + r] = m_run[r];
      Lpart[(long)bx * 64 + w * 16 + 4 * g + r] = l_run[r];
    }
  }
}

// ---------------- merge KV-split partials -> O_merged (bf16, (b,q,h*32+d)) ----------------
__global__ void merge_kernel(const float* __restrict__ Opart, const float* __restrict__ Mpart,
                             const float* __restrict__ Lpart, unsigned short* __restrict__ Om) {
  int bx = blockIdx.x;  // bh*16 + qt
  int bh = bx >> 4, qt = bx & 15;
  int row = threadIdx.x >> 2;
  int d0 = (threadIdx.x & 3) * 8;
  long pbase = (long)bx * 8;
  float mg = -1e30f, ms[8];
#pragma unroll
  for (int si = 0; si < 8; si++) {
    ms[si] = Mpart[(pbase + si) * 64 + row];
    mg = fmaxf(mg, ms[si]);
  }
  float Lg = 0.f;
  float o[8] = {0.f, 0.f, 0.f, 0.f, 0.f, 0.f, 0.f, 0.f};
#pragma unroll
  for (int si = 0; si < 8; si++) {
    float wsc = __expf(ms[si] - mg);
    Lg += Lpart[(pbase + si) * 64 + row] * wsc;
    const float* op = Opart + (pbase + si) * 2048 + row * 32 + d0;
#pragma unroll
    for (int j = 0; j < 8; j++) o[j] += op[j] * wsc;
  }
  float inv = 1.0f / Lg;
  int b = bh >> 3, h = bh & 7;
  unsigned short* dst = Om + ((long)(b * NQ + qt * 64 + row)) * DM + h * DH + d0;
  unsigned int u[4];
#pragma unroll
  for (int j = 0; j < 4; j++)
    u[j] = (unsigned int)f2bf(o[2 * j] * inv) | ((unsigned int)f2bf(o[2 * j + 1] * inv) << 16);
  *(uint4*)dst = make_uint4(u[0], u[1], u[2], u[3]);
}

// ---------------- output projection + residual: out = q + Om @ Wo^T ----------------
__global__ void outproj_kernel(const unsigned short* __restrict__ Om, const unsigned short* __restrict__ Wob,
                               const float* __restrict__ qin, float* __restrict__ out) {
  int w = threadIdx.x >> 6, lane = threadIdx.x & 63;
  int c = lane & 15, g = lane >> 4;
  int mbase = blockIdx.x * 64 + w * 16;
  f32x4 acc[16];
#pragma unroll
  for (int i = 0; i < 16; i++) acc[i] = (f32x4){0.f, 0.f, 0.f, 0.f};
  const unsigned short* arow = Om + (long)(mbase + c) * DM + g * 8;
#pragma unroll
  for (int ks = 0; ks < 8; ks++) {
    bf16x8 af = *(const bf16x8*)(arow + ks * 32);
#pragma unroll
    for (int nt = 0; nt < 16; nt++) {
      bf16x8 bf = *(const bf16x8*)(Wob + (long)(nt * 16 + c) * DM + ks * 32 + g * 8);
      acc[nt] = __builtin_amdgcn_mfma_f32_16x16x32_bf16(af, bf, acc[nt], 0, 0, 0);
    }
  }
#pragma unroll
  for (int nt = 0; nt < 16; nt++) {
#pragma unroll
    for (int r = 0; r < 4; r++) {
      int m = mbase + 4 * g + r;
      int n = nt * 16 + c;
      out[(long)m * DM + n] = qin[(long)m * DM + n] + acc[nt][r];
    }
  }
}

extern "C" void kernel_launch(void* const* d_in, const int* in_sizes, int n_in,
                              void* d_out, int out_size, void* d_ws, size_t ws_size,
                              hipStream_t stream) {
  (void)in_sizes; (void)n_in; (void)out_size; (void)ws_size;
  const float* q    = (const float*)d_in[0];
  const float* kv   = (const float*)d_in[1];
  const float* bias = (const float*)d_in[2];
  const float* Wq   = (const float*)d_in[3];
  const float* Wk   = (const float*)d_in[4];
  const float* Wv   = (const float*)d_in[5];
  const float* Wo   = (const float*)d_in[6];
  const float* gq   = (const float*)d_in[7];
  const float* bq   = (const float*)d_in[8];
  const float* gkv  = (const float*)d_in[9];
  const float* bkv  = (const float*)d_in[10];
  float* out = (float*)d_out;

  char* ws = (char*)d_ws;
  size_t off = 0;
  auto alloc = [&](size_t bytes) -> void* {
    void* p = ws + off;
    off += (bytes + 255) & ~(size_t)255;
    return p;
  };
  unsigned short* Wqb  = (unsigned short*)alloc(65536 * 2);
  unsigned short* Wkb  = (unsigned short*)alloc(65536 * 2);
  unsigned short* Wvb  = (unsigned short*)alloc(65536 * 2);
  unsigned short* Wob  = (unsigned short*)alloc(65536 * 2);
  unsigned short* qn   = (unsigned short*)alloc((size_t)2048 * 256 * 2);
  unsigned short* kvn  = (unsigned short*)alloc((size_t)16384 * 256 * 2);
  unsigned short* Qw   = (unsigned short*)alloc((size_t)2048 * 256 * 2);
  unsigned short* Kw   = (unsigned short*)alloc((size_t)16384 * 256 * 2);
  unsigned short* Vtw  = (unsigned short*)alloc((size_t)16384 * 256 * 2);
  float* Opart = (float*)alloc((size_t)2048 * 2048 * 4);
  float* Mpart = (float*)alloc((size_t)2048 * 64 * 4);
  float* Lpart = (float*)alloc((size_t)2048 * 64 * 4);
  unsigned short* Om   = (unsigned short*)alloc((size_t)2048 * 256 * 2);

  w2bf_kernel<<<64, 256, 0, stream>>>(Wq, Wqb);
  w2bf_kernel<<<64, 256, 0, stream>>>(Wk, Wkb);
  w2bf_kernel<<<64, 256, 0, stream>>>(Wv, Wvb);
  w2bf_kernel<<<64, 256, 0, stream>>>(Wo, Wob);

  ln_kernel<<<288, 256, 0, stream>>>(q, kv, gq, bq, gkv, bkv, qn, kvn);

  proj_kernel<<<32, 256, 0, stream>>>(qn, Wqb, Qw, NQ, 0);
  proj_kernel<<<256, 256, 0, stream>>>(kvn, Wkb, Kw, NKV, 0);
  proj_kernel<<<256, 256, 0, stream>>>(kvn, Wvb, Vtw, NKV, 1);

  attn_kernel<<<2048, 256, 0, stream>>>(Qw, Kw, Vtw, bias, Opart, Mpart, Lpart);

  merge_kernel<<<256, 256, 0, stream>>>(Opart, Mpart, Lpart, Om);

  outproj_kernel<<<32, 256, 0, stream>>>(Om, Wob, q, out);
}